// Round 2
// baseline (622.230 us; speedup 1.0000x reference)
//
#include <hip/hip_runtime.h>
#include <hip/hip_bf16.h>
#include <math.h>

typedef __bf16 bf16x8 __attribute__((ext_vector_type(8)));
typedef float  f32x4  __attribute__((ext_vector_type(4)));

#define T_SEQ 2048
#define NH    16
#define HD    64
#define DM    1024

__device__ __forceinline__ f32x4 mfma16(bf16x8 a, bf16x8 b, f32x4 c) {
    return __builtin_amdgcn_mfma_f32_16x16x32_bf16(a, b, c, 0, 0, 0);
}

// split 8 consecutive fp32 into bf16 hi + lo (x ~= hi + lo, rel err ~2^-16)
__device__ __forceinline__ void split8(const float* src, bf16x8& hh, bf16x8& ll) {
    f32x4 x0 = *(const f32x4*)src;
    f32x4 x1 = *(const f32x4*)(src + 4);
#pragma unroll
    for (int j = 0; j < 4; ++j) {
        __bf16 h0 = (__bf16)x0[j];
        hh[j]     = h0;  ll[j]     = (__bf16)(x0[j] - (float)h0);
        __bf16 h1 = (__bf16)x1[j];
        hh[4 + j] = h1;  ll[4 + j] = (__bf16)(x1[j] - (float)h1);
    }
}

__device__ __forceinline__ void trunc8(const float* src, bf16x8& hh) {
    f32x4 x0 = *(const f32x4*)src;
    f32x4 x1 = *(const f32x4*)(src + 4);
#pragma unroll
    for (int j = 0; j < 4; ++j) {
        hh[j]     = (__bf16)x0[j];
        hh[4 + j] = (__bf16)x1[j];
    }
}

// 64x64-tile GEMM: C[M,N] = A[M,K] @ B[K,N] (+bias fp32, +epilogue)
// AMODE: 0 = A bf16; 1 = A fp32 -> bf16 trunc; 2 = A fp32 -> hi/lo split
// BMODE: 1 = B fp32 -> bf16 trunc; 2 = B fp32 -> hi/lo split
// OUTF32: 1 = write fp32, else bf16
// EPI: 0 = bias only; 1 = RoPE (q path, N-tile == one head); 2 = bias then *t
template <int AMODE, int BMODE, int OUTF32, int EPI>
__global__ __launch_bounds__(256)
void gemm64(const void* __restrict__ Ap, const float* __restrict__ Bp,
            const float* __restrict__ bias, void* __restrict__ Cp,
            int M, int N, int K)
{
    __shared__ __attribute__((aligned(16))) __bf16 As_hi[64 * 32];
    __shared__ __attribute__((aligned(16))) __bf16 As_lo[64 * 32];
    __shared__ __attribute__((aligned(16))) __bf16 Bst_hi[64 * 32];  // [n][k]
    __shared__ __attribute__((aligned(16))) __bf16 Bst_lo[64 * 32];

    const int tid  = threadIdx.x;
    const int w    = tid >> 6;
    const int lane = tid & 63;
    const int l16  = lane & 15;
    const int quad = lane >> 4;
    const int m0   = blockIdx.y * 64;
    const int n0   = blockIdx.x * 64;

    f32x4 acc[4];
#pragma unroll
    for (int i = 0; i < 4; ++i) acc[i] = (f32x4)0.0f;

    const int arow = tid >> 2, akc = (tid & 3) * 8;   // A tile: 64 rows x 32 k
    const int bkr  = tid >> 3, bnc = (tid & 7) * 8;   // B tile: 32 k x 64 n

    for (int k0 = 0; k0 < K; k0 += 32) {
        __syncthreads();
        if (AMODE == 0) {
            const __bf16* Ab = (const __bf16*)Ap;
            *(bf16x8*)&As_hi[arow * 32 + akc] =
                *(const bf16x8*)&Ab[(size_t)(m0 + arow) * K + k0 + akc];
        } else if (AMODE == 1) {
            bf16x8 hh;
            trunc8((const float*)Ap + (size_t)(m0 + arow) * K + k0 + akc, hh);
            *(bf16x8*)&As_hi[arow * 32 + akc] = hh;
        } else {
            bf16x8 hh, ll;
            split8((const float*)Ap + (size_t)(m0 + arow) * K + k0 + akc, hh, ll);
            *(bf16x8*)&As_hi[arow * 32 + akc] = hh;
            *(bf16x8*)&As_lo[arow * 32 + akc] = ll;
        }
        {
            const float* src = Bp + (size_t)(k0 + bkr) * N + n0 + bnc;
            if (BMODE == 1) {
                bf16x8 hh;
                trunc8(src, hh);
#pragma unroll
                for (int j = 0; j < 8; ++j) Bst_hi[(bnc + j) * 32 + bkr] = hh[j];
            } else {
                bf16x8 hh, ll;
                split8(src, hh, ll);
#pragma unroll
                for (int j = 0; j < 8; ++j) {
                    Bst_hi[(bnc + j) * 32 + bkr] = hh[j];
                    Bst_lo[(bnc + j) * 32 + bkr] = ll[j];
                }
            }
        }
        __syncthreads();

        const int r16 = 16 * w + l16;
        bf16x8 ah = *(const bf16x8*)&As_hi[r16 * 32 + quad * 8];
        bf16x8 al;
        if (AMODE == 2) al = *(const bf16x8*)&As_lo[r16 * 32 + quad * 8];
#pragma unroll
        for (int cb = 0; cb < 4; ++cb) {
            bf16x8 bh = *(const bf16x8*)&Bst_hi[(cb * 16 + l16) * 32 + quad * 8];
            acc[cb] = mfma16(ah, bh, acc[cb]);
            if (AMODE == 2) acc[cb] = mfma16(al, bh, acc[cb]);
            if (BMODE == 2) {
                bf16x8 bl = *(const bf16x8*)&Bst_lo[(cb * 16 + l16) * 32 + quad * 8];
                acc[cb] = mfma16(ah, bl, acc[cb]);
            }
        }
    }

    float bias_v[4];
#pragma unroll
    for (int cb = 0; cb < 4; ++cb)
        bias_v[cb] = bias ? bias[n0 + cb * 16 + l16] : 0.0f;

    if (EPI == 1) {  // RoPE (q): pair (d, d+32) lives in (cb, cb+2) of same lane
        float* Cf = (float*)Cp;
#pragma unroll
        for (int r = 0; r < 4; ++r) {
            int   m = m0 + 16 * w + quad * 4 + r;
            float t = (float)(m & (T_SEQ - 1));
#pragma unroll
            for (int cb = 0; cb < 2; ++cb) {
                int   d   = cb * 16 + l16;
                float inv = powf(10000.0f, -(float)d * (1.0f / 32.0f));
                float sv, cv;
                sincosf(t * inv, &sv, &cv);
                float lo = acc[cb][r]     + bias_v[cb];
                float hi = acc[cb + 2][r] + bias_v[cb + 2];
                Cf[(size_t)m * N + n0 + d]      = lo * cv - hi * sv;
                Cf[(size_t)m * N + n0 + d + 32] = hi * cv + lo * sv;
            }
        }
    } else {
#pragma unroll
        for (int r = 0; r < 4; ++r) {
            int   m     = m0 + 16 * w + quad * 4 + r;
            float scale = (EPI == 2) ? (float)(m & (T_SEQ - 1)) : 1.0f;
#pragma unroll
            for (int cb = 0; cb < 4; ++cb) {
                float  v   = (acc[cb][r] + bias_v[cb]) * scale;
                size_t idx = (size_t)m * N + n0 + cb * 16 + l16;
                if (OUTF32) ((float*)Cp)[idx]  = v;
                else        ((__bf16*)Cp)[idx] = (__bf16)v;
            }
        }
    }
}

// Flash attention: one block = 64 q rows of one (b,h); 4 waves x 16 rows.
// q,k fp32 (split hi/lo for QK^T), v bf16, causal, online softmax.
__global__ __launch_bounds__(256)
void attn64(const float* __restrict__ qb, const float* __restrict__ kb,
            const __bf16* __restrict__ vb, __bf16* __restrict__ yb)
{
    __shared__ __attribute__((aligned(16))) __bf16 Ksh[32 * 64];
    __shared__ __attribute__((aligned(16))) __bf16 Ksl[32 * 64];
    __shared__ __attribute__((aligned(16))) __bf16 Vt[64 * 32];     // [d][key_local]
    __shared__ __attribute__((aligned(16))) __bf16 Pl[4][16][32];   // per-wave P

    const int tid  = threadIdx.x;
    const int w    = tid >> 6;
    const int lane = tid & 63;
    const int l16  = lane & 15;
    const int quad = lane >> 4;
    const int bh   = blockIdx.y, b = bh >> 4, h = bh & 15;
    const int q0   = blockIdx.x * 64;

    const int    qrow = q0 + 16 * w + l16;
    const float* qp   = qb + ((size_t)(b * T_SEQ + qrow)) * DM + h * HD;
    bf16x8 qh[2], ql[2];
#pragma unroll
    for (int s = 0; s < 2; ++s) split8(qp + s * 32 + quad * 8, qh[s], ql[s]);

    f32x4 o[4];
#pragma unroll
    for (int i = 0; i < 4; ++i) o[i] = (f32x4)0.0f;
    float m_i[4] = {-1e30f, -1e30f, -1e30f, -1e30f};
    float l_i[4] = {0.f, 0.f, 0.f, 0.f};

    const int srow = tid >> 3, sc8 = (tid & 7) * 8;   // staging: 32 rows x 64 cols

    for (int j0 = 0; j0 <= q0 + 63; j0 += 32) {
        __syncthreads();
        {
            bf16x8 hh, ll;
            split8(kb + ((size_t)(b * T_SEQ + j0 + srow)) * DM + h * HD + sc8, hh, ll);
            *(bf16x8*)&Ksh[srow * 64 + sc8] = hh;
            *(bf16x8*)&Ksl[srow * 64 + sc8] = ll;

            bf16x8 vv = *(const bf16x8*)&vb[((size_t)(b * T_SEQ + j0 + srow)) * DM + h * HD + sc8];
#pragma unroll
            for (int j = 0; j < 8; ++j) Vt[(sc8 + j) * 32 + srow] = vv[j];
        }
        __syncthreads();

        f32x4 s0 = (f32x4)0.0f, s1 = (f32x4)0.0f;
#pragma unroll
        for (int s = 0; s < 2; ++s) {
            bf16x8 kh0 = *(const bf16x8*)&Ksh[l16 * 64 + s * 32 + quad * 8];
            bf16x8 kl0 = *(const bf16x8*)&Ksl[l16 * 64 + s * 32 + quad * 8];
            bf16x8 kh1 = *(const bf16x8*)&Ksh[(16 + l16) * 64 + s * 32 + quad * 8];
            bf16x8 kl1 = *(const bf16x8*)&Ksl[(16 + l16) * 64 + s * 32 + quad * 8];
            s0 = mfma16(qh[s], kh0, s0);
            s0 = mfma16(ql[s], kh0, s0);
            s0 = mfma16(qh[s], kl0, s0);
            s1 = mfma16(qh[s], kh1, s1);
            s1 = mfma16(ql[s], kh1, s1);
            s1 = mfma16(qh[s], kl1, s1);
        }

#pragma unroll
        for (int r = 0; r < 4; ++r) {
            int   qr  = q0 + 16 * w + quad * 4 + r;
            float sc0 = s0[r] * 0.125f;
            float sc1 = s1[r] * 0.125f;
            if (j0 + l16 > qr)      sc0 = -1e30f;
            if (j0 + 16 + l16 > qr) sc1 = -1e30f;
            float rm = fmaxf(sc0, sc1);
#pragma unroll
            for (int off = 8; off > 0; off >>= 1) rm = fmaxf(rm, __shfl_xor(rm, off));
            float mn = fmaxf(m_i[r], rm);
            float p0 = expf(sc0 - mn);
            float p1 = expf(sc1 - mn);
            float rs = p0 + p1;
#pragma unroll
            for (int off = 8; off > 0; off >>= 1) rs += __shfl_xor(rs, off);
            float alpha = expf(m_i[r] - mn);
            l_i[r] = l_i[r] * alpha + rs;
            m_i[r] = mn;
#pragma unroll
            for (int cb = 0; cb < 4; ++cb) o[cb][r] *= alpha;
            Pl[w][quad * 4 + r][l16]      = (__bf16)p0;
            Pl[w][quad * 4 + r][16 + l16] = (__bf16)p1;
        }
        __syncthreads();

        bf16x8 pa = *(const bf16x8*)&Pl[w][l16][quad * 8];
#pragma unroll
        for (int cb = 0; cb < 4; ++cb) {
            bf16x8 vbf = *(const bf16x8*)&Vt[(cb * 16 + l16) * 32 + quad * 8];
            o[cb] = mfma16(pa, vbf, o[cb]);
        }
    }

#pragma unroll
    for (int r = 0; r < 4; ++r) {
        int   qr   = q0 + 16 * w + quad * 4 + r;
        float invl = 1.0f / l_i[r];
#pragma unroll
        for (int cb = 0; cb < 4; ++cb) {
            yb[((size_t)(b * T_SEQ + qr)) * DM + h * HD + cb * 16 + l16] =
                (__bf16)(o[cb][r] * invl);
        }
    }
}

extern "C" void kernel_launch(void* const* d_in, const int* in_sizes, int n_in,
                              void* d_out, int out_size, void* d_ws, size_t ws_size,
                              hipStream_t stream)
{
    (void)in_sizes; (void)n_in; (void)out_size; (void)ws_size;

    // Reference dtypes: everything float32 (mask int32, unused - causal applied analytically)
    const float* x   = (const float*)d_in[0];
    const float* Wq  = (const float*)d_in[2];
    const float* bq  = (const float*)d_in[3];
    const float* Wkv = (const float*)d_in[4];
    const float* bkv = (const float*)d_in[5];
    const float* Wk  = (const float*)d_in[6];
    const float* bk  = (const float*)d_in[7];
    const float* Wv  = (const float*)d_in[8];
    const float* bv  = (const float*)d_in[9];
    const float* Wo  = (const float*)d_in[10];
    const float* bo  = (const float*)d_in[11];
    const float* Wkr = (const float*)d_in[12];

    const int BT = 2 * T_SEQ;   // 4096 rows

    char*   p   = (char*)d_ws;
    float*  qf  = (float*)p;  p += (size_t)BT * DM * 4;    // 16 MB  roped q (fp32)
    float*  kvf = (float*)p;  p += (size_t)BT * 256 * 4;   //  4 MB  kv (fp32)
    float*  ksf = (float*)p;  p += (size_t)BT * DM * 4;    // 16 MB  ksc -> krot in-place
    __bf16* vbb = (__bf16*)p; p += (size_t)BT * DM * 2;    //  8 MB  v (bf16)
    __bf16* ybb = (__bf16*)p; p += (size_t)BT * DM * 2;    //  8 MB  y (bf16)

    dim3 blk(256);
    // q = RoPE(x@Wq + bq)                 [4096,1024] fp32, split x split
    gemm64<2, 2, 1, 1><<<dim3(16, 64), blk, 0, stream>>>(x, Wq, bq, qf, BT, DM, DM);
    // kv = x@Wkv + bkv                    [4096,256]  fp32, split x split
    gemm64<2, 2, 1, 0><<<dim3(4, 64), blk, 0, stream>>>(x, Wkv, bkv, kvf, BT, 256, DM);
    // ksc = (kv@Wk + bk) * t              [4096,1024] fp32, split x split
    gemm64<2, 2, 1, 2><<<dim3(16, 64), blk, 0, stream>>>(kvf, Wk, bk, ksf, BT, DM, 256);
    // v = kv@Wv + bv                      [4096,1024] bf16, trunc x trunc
    gemm64<1, 1, 0, 0><<<dim3(16, 64), blk, 0, stream>>>(kvf, Wv, bv, vbb, BT, DM, 256);
    // krot = ksc@Wkr (per head, in-place) [65536,64]  fp32, split x split
    gemm64<2, 2, 1, 0><<<dim3(1, 1024), blk, 0, stream>>>(ksf, Wkr, nullptr, ksf, BT * NH, HD, HD);
    // flash attention -> y bf16
    attn64<<<dim3(T_SEQ / 64, 2 * NH), blk, 0, stream>>>(qf, ksf, vbb, ybb);
    // out = y@Wo + bo                     [4096,1024] fp32 -> d_out
    gemm64<0, 1, 1, 0><<<dim3(16, 64), blk, 0, stream>>>(ybb, Wo, bo, (float*)d_out, BT, DM, DM);
}

// Round 3
// 469.051 us; speedup vs baseline: 1.3266x; 1.3266x over previous
//
#include <hip/hip_runtime.h>
#include <hip/hip_bf16.h>
#include <math.h>

typedef __bf16 bf16x8 __attribute__((ext_vector_type(8)));
typedef __bf16 bf16x2 __attribute__((ext_vector_type(2)));
typedef float  f32x4  __attribute__((ext_vector_type(4)));

#define T_SEQ 2048
#define NH    16
#define HD    64
#define DM    1024

__device__ __forceinline__ f32x4 mfma16(bf16x8 a, bf16x8 b, f32x4 c) {
    return __builtin_amdgcn_mfma_f32_16x16x32_bf16(a, b, c, 0, 0, 0);
}

// split 8 consecutive fp32 into bf16 hi + lo (x ~= hi + lo, rel err ~2^-16)
__device__ __forceinline__ void split8(const float* src, bf16x8& hh, bf16x8& ll) {
    f32x4 x0 = *(const f32x4*)src;
    f32x4 x1 = *(const f32x4*)(src + 4);
#pragma unroll
    for (int j = 0; j < 4; ++j) {
        __bf16 h0 = (__bf16)x0[j];
        hh[j]     = h0;  ll[j]     = (__bf16)(x0[j] - (float)h0);
        __bf16 h1 = (__bf16)x1[j];
        hh[4 + j] = h1;  ll[4 + j] = (__bf16)(x1[j] - (float)h1);
    }
}

__device__ __forceinline__ void trunc8(const float* src, bf16x8& hh) {
    f32x4 x0 = *(const f32x4*)src;
    f32x4 x1 = *(const f32x4*)(src + 4);
#pragma unroll
    for (int j = 0; j < 4; ++j) {
        hh[j]     = (__bf16)x0[j];
        hh[4 + j] = (__bf16)x1[j];
    }
}

// W2[kc][h*64+d] = sum_j Wk[kc][h*64+j] * Wkr[j][d]   (row 256 = bias row from bk)
__global__ void fuse_w2(const float* __restrict__ Wk, const float* __restrict__ Wkr,
                        const float* __restrict__ bk,
                        float* __restrict__ W2, float* __restrict__ b2)
{
    int h = blockIdx.y, row = blockIdx.x, d = threadIdx.x;
    float acc = 0.0f;
    if (row < 256) {
#pragma unroll 8
        for (int j = 0; j < 64; ++j)
            acc += Wk[(size_t)row * DM + h * HD + j] * Wkr[j * HD + d];
        W2[(size_t)row * DM + h * HD + d] = acc;
    } else {
#pragma unroll 8
        for (int j = 0; j < 64; ++j)
            acc += bk[h * HD + j] * Wkr[j * HD + d];
        b2[h * HD + d] = acc;
    }
}

// 64x64-tile GEMM: C[M,N] = A[M,K] @ B[K,N] (+bias fp32, +epilogue)
// AMODE: 0 = A bf16; 1 = A fp32 trunc; 2 = A fp32 hi/lo split
// BMODE: 1 = B fp32 trunc; 2 = B fp32 hi/lo split
// OUTM:  0 = bf16; 1 = fp32; 2 = split dual bf16 (Cp=hi, Cp2=lo)
// EPI:   0 = bias; 1 = RoPE*0.125 (q path; forces split out); 2 = bias then *t
template <int AMODE, int BMODE, int OUTM, int EPI>
__global__ __launch_bounds__(256)
void gemm64(const void* __restrict__ Ap, const float* __restrict__ Bp,
            const float* __restrict__ bias, void* __restrict__ Cp,
            void* __restrict__ Cp2, int M, int N, int K)
{
    __shared__ __attribute__((aligned(16))) __bf16 As_hi[64 * 32];
    __shared__ __attribute__((aligned(16))) __bf16 As_lo[64 * 32];
    __shared__ __attribute__((aligned(16))) __bf16 Bst_hi[64 * 32];  // [n][k]
    __shared__ __attribute__((aligned(16))) __bf16 Bst_lo[64 * 32];

    const int tid  = threadIdx.x;
    const int w    = tid >> 6;
    const int lane = tid & 63;
    const int l16  = lane & 15;
    const int quad = lane >> 4;
    const int m0   = blockIdx.y * 64;
    const int n0   = blockIdx.x * 64;

    f32x4 acc[4];
#pragma unroll
    for (int i = 0; i < 4; ++i) acc[i] = (f32x4)0.0f;

    const int arow = tid >> 2, akc = (tid & 3) * 8;   // A tile: 64 rows x 32 k
    const int bkr  = tid >> 3, bnc = (tid & 7) * 8;   // B tile: 32 k x 64 n

    for (int k0 = 0; k0 < K; k0 += 32) {
        __syncthreads();
        if (AMODE == 0) {
            const __bf16* Ab = (const __bf16*)Ap;
            *(bf16x8*)&As_hi[arow * 32 + akc] =
                *(const bf16x8*)&Ab[(size_t)(m0 + arow) * K + k0 + akc];
        } else if (AMODE == 1) {
            bf16x8 hh;
            trunc8((const float*)Ap + (size_t)(m0 + arow) * K + k0 + akc, hh);
            *(bf16x8*)&As_hi[arow * 32 + akc] = hh;
        } else {
            bf16x8 hh, ll;
            split8((const float*)Ap + (size_t)(m0 + arow) * K + k0 + akc, hh, ll);
            *(bf16x8*)&As_hi[arow * 32 + akc] = hh;
            *(bf16x8*)&As_lo[arow * 32 + akc] = ll;
        }
        {
            const float* src = Bp + (size_t)(k0 + bkr) * N + n0 + bnc;
            if (BMODE == 1) {
                bf16x8 hh;
                trunc8(src, hh);
#pragma unroll
                for (int j = 0; j < 8; ++j) Bst_hi[(bnc + j) * 32 + bkr] = hh[j];
            } else {
                bf16x8 hh, ll;
                split8(src, hh, ll);
#pragma unroll
                for (int j = 0; j < 8; ++j) {
                    Bst_hi[(bnc + j) * 32 + bkr] = hh[j];
                    Bst_lo[(bnc + j) * 32 + bkr] = ll[j];
                }
            }
        }
        __syncthreads();

        const int r16 = 16 * w + l16;
        bf16x8 ah = *(const bf16x8*)&As_hi[r16 * 32 + quad * 8];
        bf16x8 al;
        if (AMODE == 2) al = *(const bf16x8*)&As_lo[r16 * 32 + quad * 8];
#pragma unroll
        for (int cb = 0; cb < 4; ++cb) {
            bf16x8 bh = *(const bf16x8*)&Bst_hi[(cb * 16 + l16) * 32 + quad * 8];
            acc[cb] = mfma16(ah, bh, acc[cb]);
            if (AMODE == 2) acc[cb] = mfma16(al, bh, acc[cb]);
            if (BMODE == 2) {
                bf16x8 bl = *(const bf16x8*)&Bst_lo[(cb * 16 + l16) * 32 + quad * 8];
                acc[cb] = mfma16(ah, bl, acc[cb]);
            }
        }
    }

    float bias_v[4];
#pragma unroll
    for (int cb = 0; cb < 4; ++cb)
        bias_v[cb] = bias ? bias[n0 + cb * 16 + l16] : 0.0f;

    if (EPI == 1) {  // RoPE (q): pair (d, d+32) lives in (cb, cb+2); *0.125 folded
        __bf16* Chi = (__bf16*)Cp;
        __bf16* Clo = (__bf16*)Cp2;
#pragma unroll
        for (int r = 0; r < 4; ++r) {
            int   m = m0 + 16 * w + quad * 4 + r;
            float t = (float)(m & (T_SEQ - 1));
#pragma unroll
            for (int cb = 0; cb < 2; ++cb) {
                int   d   = cb * 16 + l16;
                float inv = powf(10000.0f, -(float)d * (1.0f / 32.0f));
                float sv, cv;
                sincosf(t * inv, &sv, &cv);
                float lo = acc[cb][r]     + bias_v[cb];
                float hi = acc[cb + 2][r] + bias_v[cb + 2];
                float v0 = (lo * cv - hi * sv) * 0.125f;
                float v1 = (hi * cv + lo * sv) * 0.125f;
                size_t i0 = (size_t)m * N + n0 + d;
                size_t i1 = i0 + 32;
                __bf16 h0 = (__bf16)v0, h1 = (__bf16)v1;
                Chi[i0] = h0; Clo[i0] = (__bf16)(v0 - (float)h0);
                Chi[i1] = h1; Clo[i1] = (__bf16)(v1 - (float)h1);
            }
        }
    } else {
#pragma unroll
        for (int r = 0; r < 4; ++r) {
            int   m     = m0 + 16 * w + quad * 4 + r;
            float scale = (EPI == 2) ? (float)(m & (T_SEQ - 1)) : 1.0f;
#pragma unroll
            for (int cb = 0; cb < 4; ++cb) {
                float  v   = (acc[cb][r] + bias_v[cb]) * scale;
                size_t idx = (size_t)m * N + n0 + cb * 16 + l16;
                if (OUTM == 1)      ((float*)Cp)[idx]  = v;
                else if (OUTM == 0) ((__bf16*)Cp)[idx] = (__bf16)v;
                else {
                    __bf16 hb = (__bf16)v;
                    ((__bf16*)Cp)[idx]  = hb;
                    ((__bf16*)Cp2)[idx] = (__bf16)(v - (float)hb);
                }
            }
        }
    }
}

// v [B*T, DM] bf16  ->  vtg [B*NH, HD, T_SEQ] bf16 (per-(b,h) transposed)
__global__ __launch_bounds__(256)
void transpose_v(const __bf16* __restrict__ vb, __bf16* __restrict__ vtg)
{
    __shared__ __attribute__((aligned(16))) __bf16 tile[64 * 72];  // [t][d], pad 8

    const int tid = threadIdx.x;
    const int bh  = blockIdx.y, b = bh >> 4, h = bh & 15;
    const int t0  = blockIdx.x * 64;

#pragma unroll
    for (int it = 0; it < 2; ++it) {
        int r = it * 32 + (tid >> 3), c8 = (tid & 7) * 8;
        *(bf16x8*)&tile[r * 72 + c8] =
            *(const bf16x8*)&vb[(size_t)(b * T_SEQ + t0 + r) * DM + h * HD + c8];
    }
    __syncthreads();

    const int d  = tid & 63;          // whole wave covers all 64 d -> conflict-free reads
    const int tc = (tid >> 6) * 16;   // wave-uniform t-chunk
    bf16x8 o0, o1;
#pragma unroll
    for (int j = 0; j < 8; ++j) {
        o0[j] = tile[(tc + j) * 72 + d];
        o1[j] = tile[(tc + 8 + j) * 72 + d];
    }
    __bf16* dst = &vtg[(size_t)(bh * HD + d) * T_SEQ + t0 + tc];
    *(bf16x8*)dst       = o0;
    *(bf16x8*)(dst + 8) = o1;
}

// Flash attention v2: paired q-tiles (uniform work), 64-key steps, all-bf16 staging.
// qhi/qlo pre-scaled by 0.125; khi/klo split bf16; vtg pre-transposed [bh][d][t].
__global__ __launch_bounds__(256)
void attn_v2(const __bf16* __restrict__ qhi, const __bf16* __restrict__ qlo,
             const __bf16* __restrict__ khi, const __bf16* __restrict__ klo,
             const __bf16* __restrict__ vtg, __bf16* __restrict__ yb)
{
    __shared__ __attribute__((aligned(16))) __bf16 Kh[64 * 64];
    __shared__ __attribute__((aligned(16))) __bf16 Kl[64 * 64];
    __shared__ __attribute__((aligned(16))) __bf16 Vt[64 * 64];      // [d][key]
    __shared__ __attribute__((aligned(16))) __bf16 Pt[4][64 * 18];   // [key][qrow], S=18

    const int tid  = threadIdx.x;
    const int w    = tid >> 6;
    const int lane = tid & 63;
    const int l16  = lane & 15;
    const int quad = lane >> 4;
    const int bh   = blockIdx.y, b = bh >> 4, h = bh & 15;

    const int srow = tid >> 3, sc8 = (tid & 7) * 8;   // staging: 32 rows x 64 cols
    __bf16* ptw = &Pt[w][0];

#pragma unroll
    for (int half = 0; half < 2; ++half) {
        const int tile = half ? (31 - blockIdx.x) : blockIdx.x;
        const int q0   = tile * 64;

        // Q fragments (A-layout, m = l16), pre-scaled hi/lo
        const int     qrow = q0 + 16 * w + l16;
        const size_t  qoff = (size_t)(b * T_SEQ + qrow) * DM + h * HD;
        bf16x8 qh[2], ql[2];
#pragma unroll
        for (int s = 0; s < 2; ++s) {
            qh[s] = *(const bf16x8*)&qhi[qoff + s * 32 + quad * 8];
            ql[s] = *(const bf16x8*)&qlo[qoff + s * 32 + quad * 8];
        }

        f32x4 o[4];
#pragma unroll
        for (int i = 0; i < 4; ++i) o[i] = (f32x4)0.0f;
        float m_i[4] = {-1e30f, -1e30f, -1e30f, -1e30f};
        float l_i[4] = {0.f, 0.f, 0.f, 0.f};

        for (int j0 = 0; j0 <= q0; j0 += 64) {
            const bool domask = (j0 == q0);
            __syncthreads();
#pragma unroll
            for (int it = 0; it < 2; ++it) {
                int    r = it * 32 + srow;
                size_t g = (size_t)(b * T_SEQ + j0 + r) * DM + h * HD + sc8;
                *(bf16x8*)&Kh[r * 64 + sc8] = *(const bf16x8*)&khi[g];
                *(bf16x8*)&Kl[r * 64 + sc8] = *(const bf16x8*)&klo[g];
                *(bf16x8*)&Vt[r * 64 + sc8] =
                    *(const bf16x8*)&vtg[(size_t)(bh * HD + r) * T_SEQ + j0 + sc8];
            }
            __syncthreads();

            // S = Q K^T : 16 rows x 64 keys (4 col-tiles), split product
            f32x4 sa[4];
#pragma unroll
            for (int i = 0; i < 4; ++i) sa[i] = (f32x4)0.0f;
#pragma unroll
            for (int s = 0; s < 2; ++s) {
#pragma unroll
                for (int ct = 0; ct < 4; ++ct) {
                    bf16x8 kh = *(const bf16x8*)&Kh[(ct * 16 + l16) * 64 + s * 32 + quad * 8];
                    bf16x8 kl = *(const bf16x8*)&Kl[(ct * 16 + l16) * 64 + s * 32 + quad * 8];
                    sa[ct] = mfma16(qh[s], kh, sa[ct]);
                    sa[ct] = mfma16(ql[s], kh, sa[ct]);
                    sa[ct] = mfma16(qh[s], kl, sa[ct]);
                }
            }

            // online softmax (rows = quad*4+r, cols = ct*16+l16)
            float p[4][4];
#pragma unroll
            for (int r = 0; r < 4; ++r) {
                const int rq = 16 * w + quad * 4 + r;   // local row id in 0..63
                float sc[4];
#pragma unroll
                for (int ct = 0; ct < 4; ++ct) {
                    sc[ct] = sa[ct][r];
                    if (domask && (ct * 16 + l16 > rq)) sc[ct] = -1e30f;
                }
                float rm = fmaxf(fmaxf(sc[0], sc[1]), fmaxf(sc[2], sc[3]));
#pragma unroll
                for (int off = 8; off > 0; off >>= 1) rm = fmaxf(rm, __shfl_xor(rm, off));
                float mn    = fmaxf(m_i[r], rm);
                float alpha = __expf(m_i[r] - mn);
                m_i[r] = mn;
                float rs = 0.f;
#pragma unroll
                for (int ct = 0; ct < 4; ++ct) { p[r][ct] = __expf(sc[ct] - mn); rs += p[r][ct]; }
#pragma unroll
                for (int off = 8; off > 0; off >>= 1) rs += __shfl_xor(rs, off);
                l_i[r] = l_i[r] * alpha + rs;
#pragma unroll
                for (int cb = 0; cb < 4; ++cb) o[cb][r] *= alpha;
            }

            // P -> LDS transposed [key][qrow], packed b32 writes (conflict-free)
#pragma unroll
            for (int ct = 0; ct < 4; ++ct) {
                bf16x2 p01 = { (__bf16)p[0][ct], (__bf16)p[1][ct] };
                bf16x2 p23 = { (__bf16)p[2][ct], (__bf16)p[3][ct] };
                __bf16* base = &ptw[(ct * 16 + l16) * 18 + quad * 4];
                *(bf16x2*)base       = p01;
                *(bf16x2*)(base + 2) = p23;
            }

            // O += P @ V   (A = P[qrow=l16][key], B = V[key][d])
#pragma unroll
            for (int s = 0; s < 2; ++s) {
                bf16x8 pa;
#pragma unroll
                for (int jj = 0; jj < 8; ++jj)
                    pa[jj] = ptw[(s * 32 + quad * 8 + jj) * 18 + l16];
#pragma unroll
                for (int cb = 0; cb < 4; ++cb) {
                    bf16x8 vf = *(const bf16x8*)&Vt[(cb * 16 + l16) * 64 + s * 32 + quad * 8];
                    o[cb] = mfma16(pa, vf, o[cb]);
                }
            }
        }

#pragma unroll
        for (int r = 0; r < 4; ++r) {
            int   qr   = q0 + 16 * w + quad * 4 + r;
            float invl = 1.0f / l_i[r];
#pragma unroll
            for (int cb = 0; cb < 4; ++cb) {
                yb[(size_t)(b * T_SEQ + qr) * DM + h * HD + cb * 16 + l16] =
                    (__bf16)(o[cb][r] * invl);
            }
        }
    }
}

extern "C" void kernel_launch(void* const* d_in, const int* in_sizes, int n_in,
                              void* d_out, int out_size, void* d_ws, size_t ws_size,
                              hipStream_t stream)
{
    (void)in_sizes; (void)n_in; (void)out_size; (void)ws_size;

    const float* x   = (const float*)d_in[0];
    const float* Wq  = (const float*)d_in[2];
    const float* bq  = (const float*)d_in[3];
    const float* Wkv = (const float*)d_in[4];
    const float* bkv = (const float*)d_in[5];
    const float* Wk  = (const float*)d_in[6];
    const float* bk  = (const float*)d_in[7];
    const float* Wv  = (const float*)d_in[8];
    const float* bv  = (const float*)d_in[9];
    const float* Wo  = (const float*)d_in[10];
    const float* bo  = (const float*)d_in[11];
    const float* Wkr = (const float*)d_in[12];

    const int    BT = 2 * T_SEQ;            // 4096 rows
    const size_t MB = 1024 * 1024;

    char* base = (char*)d_ws;
    __bf16* qhi = (__bf16*)(base +  0 * MB);   // live 2..7
    __bf16* qlo = (__bf16*)(base +  8 * MB);   // live 2..7
    __bf16* khi = (__bf16*)(base + 16 * MB);   // live 4..7
    __bf16* klo = (__bf16*)(base + 24 * MB);   // live 4..7
    __bf16* vbb = (__bf16*)(base + 32 * MB);   // live 5..6
    __bf16* ybb = (__bf16*)(base + 32 * MB);   // live 7..8 (overlays vbb)
    float*  kvf = (float*) (base + 40 * MB);   // live 3..5
    float*  W2f = (float*) (base + 44 * MB);   // live 1..4 (1 MB)
    float*  b2f = (float*) (base + 45 * MB);   // live 1..4 (4 KB)
    __bf16* vtg = (__bf16*)(base + 40 * MB);   // live 6..7 (overlays kvf/W2f/b2f)

    dim3 blk(256);
    // 1. fused decoupled-k weight: W2 = Wk_h @ Wkr, b2 = bk_h @ Wkr (fp32 exact)
    fuse_w2<<<dim3(257, NH), dim3(64), 0, stream>>>(Wk, Wkr, bk, W2f, b2f);
    // 2. q = RoPE(x@Wq + bq) * 0.125 -> split bf16
    gemm64<2, 2, 2, 1><<<dim3(16, 64), blk, 0, stream>>>(x, Wq, bq, qhi, qlo, BT, DM, DM);
    // 3. kv = x@Wkv + bkv -> fp32
    gemm64<2, 2, 1, 0><<<dim3(4, 64), blk, 0, stream>>>(x, Wkv, bkv, kvf, nullptr, BT, 256, DM);
    // 4. k = t*(kv@W2 + b2) -> split bf16
    gemm64<2, 2, 2, 2><<<dim3(16, 64), blk, 0, stream>>>(kvf, W2f, b2f, khi, klo, BT, DM, 256);
    // 5. v = kv@Wv + bv -> bf16
    gemm64<1, 1, 0, 0><<<dim3(16, 64), blk, 0, stream>>>(kvf, Wv, bv, vbb, nullptr, BT, DM, 256);
    // 6. v -> vtg transposed [bh][d][t]
    transpose_v<<<dim3(T_SEQ / 64, 2 * NH), blk, 0, stream>>>(vbb, vtg);
    // 7. flash attention -> y bf16
    attn_v2<<<dim3(16, 2 * NH), blk, 0, stream>>>(qhi, qlo, khi, klo, vtg, ybb);
    // 8. out = y@Wo + bo -> fp32 d_out
    gemm64<0, 1, 1, 0><<<dim3(16, 64), blk, 0, stream>>>(ybb, Wo, bo, (float*)d_out, nullptr, BT, DM, DM);
}

// Round 4
// 392.735 us; speedup vs baseline: 1.5843x; 1.1943x over previous
//
#include <hip/hip_runtime.h>
#include <hip/hip_bf16.h>
#include <math.h>

typedef __bf16 bf16x8 __attribute__((ext_vector_type(8)));
typedef __bf16 bf16x2 __attribute__((ext_vector_type(2)));
typedef float  f32x4  __attribute__((ext_vector_type(4)));

#define T_SEQ 2048
#define NH    16
#define HD    64
#define DM    1024

__device__ __forceinline__ f32x4 mfma16(bf16x8 a, bf16x8 b, f32x4 c) {
    return __builtin_amdgcn_mfma_f32_16x16x32_bf16(a, b, c, 0, 0, 0);
}

// ---------------- prep kernels ----------------

// x fp32 -> xhi/xlo bf16 (row-major, same layout)
__global__ __launch_bounds__(256)
void split_x_kernel(const float* __restrict__ x, __bf16* __restrict__ xh,
                    __bf16* __restrict__ xl)
{
    size_t idx = ((size_t)blockIdx.x * 256 + threadIdx.x) * 8;
    f32x4 a0 = *(const f32x4*)&x[idx];
    f32x4 a1 = *(const f32x4*)&x[idx + 4];
    bf16x8 h, l;
#pragma unroll
    for (int j = 0; j < 4; ++j) {
        __bf16 h0 = (__bf16)a0[j];
        h[j]     = h0; l[j]     = (__bf16)(a0[j] - (float)h0);
        __bf16 h1 = (__bf16)a1[j];
        h[4 + j] = h1; l[4 + j] = (__bf16)(a1[j] - (float)h1);
    }
    *(bf16x8*)&xh[idx] = h;
    *(bf16x8*)&xl[idx] = l;
}

// in fp32 [K,N] -> out bf16 [N,K] (transposed), hi (+lo if SPLIT)
template <int SPLIT>
__global__ __launch_bounds__(256)
void tsplit(const float* __restrict__ in, __bf16* __restrict__ oh,
            __bf16* __restrict__ ol, int K, int N)
{
    __shared__ float tile[64][65];
    const int tid = threadIdx.x;
    const int n0 = blockIdx.x * 64, k0 = blockIdx.y * 64;
#pragma unroll
    for (int it = 0; it < 2; ++it) {
        int r = it * 32 + (tid >> 3), c8 = (tid & 7) * 8;
        f32x4 a0 = *(const f32x4*)&in[(size_t)(k0 + r) * N + n0 + c8];
        f32x4 a1 = *(const f32x4*)&in[(size_t)(k0 + r) * N + n0 + c8 + 4];
#pragma unroll
        for (int j = 0; j < 4; ++j) { tile[r][c8 + j] = a0[j]; tile[r][c8 + 4 + j] = a1[j]; }
    }
    __syncthreads();
    const int n = tid >> 2, kb = (tid & 3) * 16;
    bf16x8 h0, h1, l0, l1;
#pragma unroll
    for (int j = 0; j < 8; ++j) {
        float v0 = tile[kb + j][n], v1 = tile[kb + 8 + j][n];
        __bf16 hb0 = (__bf16)v0, hb1 = (__bf16)v1;
        h0[j] = hb0; h1[j] = hb1;
        if (SPLIT) { l0[j] = (__bf16)(v0 - (float)hb0); l1[j] = (__bf16)(v1 - (float)hb1); }
    }
    size_t o = (size_t)(n0 + n) * K + k0 + kb;
    *(bf16x8*)&oh[o] = h0; *(bf16x8*)&oh[o + 8] = h1;
    if (SPLIT) { *(bf16x8*)&ol[o] = l0; *(bf16x8*)&ol[o + 8] = l1; }
}

// W2 = Wk_h @ Wkr (+ b2 = bk_h @ Wkr), written transposed+split: W2t[n=h*64+d][k=row]
__global__ void fuse_w2t(const float* __restrict__ Wk, const float* __restrict__ Wkr,
                         const float* __restrict__ bk,
                         __bf16* __restrict__ W2th, __bf16* __restrict__ W2tl,
                         float* __restrict__ b2)
{
    int h = blockIdx.y, row = blockIdx.x, d = threadIdx.x;
    float acc = 0.0f;
    if (row < 256) {
#pragma unroll 8
        for (int j = 0; j < 64; ++j)
            acc += Wk[(size_t)row * DM + h * HD + j] * Wkr[j * HD + d];
        __bf16 hb = (__bf16)acc;
        W2th[(size_t)(h * HD + d) * 256 + row] = hb;
        W2tl[(size_t)(h * HD + d) * 256 + row] = (__bf16)(acc - (float)hb);
    } else {
#pragma unroll 8
        for (int j = 0; j < 64; ++j)
            acc += bk[h * HD + j] * Wkr[j * HD + d];
        b2[h * HD + d] = acc;
    }
}

// ---------------- 128x128-tile GEMM ----------------
// A bf16 [M,K] (hi + optional lo), B bf16 [N,K] transposed (hi + optional lo)
// OUTM: 0 = bf16; 1 = fp32; 2 = split dual bf16 (Cp=hi, Cp2=lo)
// EPI:  0 = bias; 1 = RoPE*0.125 -> split out; 2 = bias then *t; 3 = v->vtg transpose
template <int DUALA, int DUALB, int OUTM, int EPI>
__global__ __launch_bounds__(256)
void gemm128(const __bf16* __restrict__ Ahi, const __bf16* __restrict__ Alo,
             const __bf16* __restrict__ Bhi, const __bf16* __restrict__ Blo,
             const float* __restrict__ bias, void* __restrict__ Cp,
             void* __restrict__ Cp2, int M, int N, int K)
{
    __shared__ __attribute__((aligned(16))) char smem[36864];
    __bf16* Ah = (__bf16*)smem;               // [128][32]
    __bf16* Al = (__bf16*)(smem + 8192);
    __bf16* Bh = (__bf16*)(smem + 16384);     // [128][32] = [n][k]
    __bf16* Bl = (__bf16*)(smem + 24576);

    const int tid  = threadIdx.x;
    const int w    = tid >> 6;
    const int lane = tid & 63;
    const int l16  = lane & 15;
    const int quad = lane >> 4;
    const int wy   = w >> 1, wx = w & 1;
    const int m0   = blockIdx.y * 128;
    const int n0   = blockIdx.x * 128;

    f32x4 acc[4][4];
#pragma unroll
    for (int i = 0; i < 4; ++i)
#pragma unroll
        for (int j = 0; j < 4; ++j) acc[i][j] = (f32x4)0.0f;

    for (int k0 = 0; k0 < K; k0 += 32) {
        __syncthreads();
#pragma unroll
        for (int i = 0; i < 2; ++i) {
            int s = i * 256 + tid, row = s >> 2, c8 = (s & 3) * 8;
            *(bf16x8*)&Ah[row * 32 + c8] = *(const bf16x8*)&Ahi[(size_t)(m0 + row) * K + k0 + c8];
            if (DUALA)
                *(bf16x8*)&Al[row * 32 + c8] = *(const bf16x8*)&Alo[(size_t)(m0 + row) * K + k0 + c8];
            *(bf16x8*)&Bh[row * 32 + c8] = *(const bf16x8*)&Bhi[(size_t)(n0 + row) * K + k0 + c8];
            if (DUALB)
                *(bf16x8*)&Bl[row * 32 + c8] = *(const bf16x8*)&Blo[(size_t)(n0 + row) * K + k0 + c8];
        }
        __syncthreads();

        bf16x8 bfh[4], bfl[4];
#pragma unroll
        for (int ct = 0; ct < 4; ++ct) {
            bfh[ct] = *(const bf16x8*)&Bh[(wx * 64 + ct * 16 + l16) * 32 + quad * 8];
            if (DUALB) bfl[ct] = *(const bf16x8*)&Bl[(wx * 64 + ct * 16 + l16) * 32 + quad * 8];
        }
#pragma unroll
        for (int mf = 0; mf < 4; ++mf) {
            bf16x8 ah = *(const bf16x8*)&Ah[(wy * 64 + mf * 16 + l16) * 32 + quad * 8];
            bf16x8 al;
            if (DUALA) al = *(const bf16x8*)&Al[(wy * 64 + mf * 16 + l16) * 32 + quad * 8];
#pragma unroll
            for (int ct = 0; ct < 4; ++ct) {
                acc[mf][ct] = mfma16(ah, bfh[ct], acc[mf][ct]);
                if (DUALA) acc[mf][ct] = mfma16(al, bfh[ct], acc[mf][ct]);
                if (DUALB) acc[mf][ct] = mfma16(ah, bfl[ct], acc[mf][ct]);
            }
        }
    }

    float bias_v[4];
#pragma unroll
    for (int ct = 0; ct < 4; ++ct)
        bias_v[ct] = bias ? bias[n0 + wx * 64 + ct * 16 + l16] : 0.0f;

    if (EPI == 1) {  // RoPE (q): pair (d, d+32) = (ct, ct+2); *0.125 folded; split out
        __bf16* Chi = (__bf16*)Cp;
        __bf16* Clo = (__bf16*)Cp2;
#pragma unroll
        for (int mf = 0; mf < 4; ++mf) {
#pragma unroll
            for (int r = 0; r < 4; ++r) {
                int   m = m0 + wy * 64 + mf * 16 + quad * 4 + r;
                float t = (float)(m & (T_SEQ - 1));
#pragma unroll
                for (int ct = 0; ct < 2; ++ct) {
                    int   d   = ct * 16 + l16;
                    float inv = powf(10000.0f, -(float)d * (1.0f / 32.0f));
                    float sv, cv;
                    sincosf(t * inv, &sv, &cv);
                    float lo = acc[mf][ct][r]     + bias_v[ct];
                    float hi = acc[mf][ct + 2][r] + bias_v[ct + 2];
                    float v0 = (lo * cv - hi * sv) * 0.125f;
                    float v1 = (hi * cv + lo * sv) * 0.125f;
                    size_t i0 = (size_t)m * N + n0 + wx * 64 + d;
                    size_t i1 = i0 + 32;
                    __bf16 h0 = (__bf16)v0, h1 = (__bf16)v1;
                    Chi[i0] = h0; Clo[i0] = (__bf16)(v0 - (float)h0);
                    Chi[i1] = h1; Clo[i1] = (__bf16)(v1 - (float)h1);
                }
            }
        }
    } else if (EPI == 3) {  // v epilogue: write vtg[bh][d][t] via per-wave LDS transpose
        __syncthreads();    // staging LDS reuse across waves
        __bf16* vt = (__bf16*)(smem + w * 9216);   // [64][72]
#pragma unroll
        for (int mf = 0; mf < 4; ++mf)
#pragma unroll
            for (int ct = 0; ct < 4; ++ct)
#pragma unroll
                for (int r = 0; r < 4; ++r)
                    vt[(ct * 16 + l16) * 72 + mf * 16 + quad * 4 + r] =
                        (__bf16)(acc[mf][ct][r] + bias_v[ct]);
        const int bb   = m0 >> 11;
        const int head = (n0 + wx * 64) >> 6;
        const int bh   = bb * 16 + head;
        __bf16* out    = (__bf16*)Cp;
        size_t  gbase  = ((size_t)(bh * 64 + lane)) * T_SEQ + (m0 & (T_SEQ - 1)) + wy * 64;
#pragma unroll
        for (int j8 = 0; j8 < 8; ++j8)
            *(bf16x8*)&out[gbase + j8 * 8] = *(const bf16x8*)&vt[lane * 72 + j8 * 8];
    } else {
#pragma unroll
        for (int mf = 0; mf < 4; ++mf) {
#pragma unroll
            for (int r = 0; r < 4; ++r) {
                int   m     = m0 + wy * 64 + mf * 16 + quad * 4 + r;
                float scale = (EPI == 2) ? (float)(m & (T_SEQ - 1)) : 1.0f;
#pragma unroll
                for (int ct = 0; ct < 4; ++ct) {
                    float  v   = (acc[mf][ct][r] + bias_v[ct]) * scale;
                    size_t idx = (size_t)m * N + n0 + wx * 64 + ct * 16 + l16;
                    if (OUTM == 1)      ((float*)Cp)[idx]  = v;
                    else if (OUTM == 0) ((__bf16*)Cp)[idx] = (__bf16)v;
                    else {
                        __bf16 hb = (__bf16)v;
                        ((__bf16*)Cp)[idx]  = hb;
                        ((__bf16*)Cp2)[idx] = (__bf16)(v - (float)hb);
                    }
                }
            }
        }
    }
}

// ---------------- flash attention ----------------
// paired q-tiles, 64-key steps, padded LDS (stride 72), XCD-swizzled grid
#define KS 72
__global__ __launch_bounds__(256)
void attn_v3(const __bf16* __restrict__ qhi, const __bf16* __restrict__ qlo,
             const __bf16* __restrict__ khi, const __bf16* __restrict__ klo,
             const __bf16* __restrict__ vtg, __bf16* __restrict__ yb)
{
    __shared__ __attribute__((aligned(16))) __bf16 Kh[64 * KS];
    __shared__ __attribute__((aligned(16))) __bf16 Kl[64 * KS];
    __shared__ __attribute__((aligned(16))) __bf16 Vt[64 * KS];      // [d][key]
    __shared__ __attribute__((aligned(16))) __bf16 Pt[4][64 * 18];   // [key][qrow]

    const int tid  = threadIdx.x;
    const int w    = tid >> 6;
    const int lane = tid & 63;
    const int l16  = lane & 15;
    const int quad = lane >> 4;

    // XCD swizzle: all 16 tile-blocks of one (b,h) land on one XCD (lin%8 fixed)
    const int g  = blockIdx.x;
    const int tx = (g >> 3) & 15;
    const int bh = (g & 7) + 8 * (g >> 7);
    const int b  = bh >> 4, h = bh & 15;

    const int srow = tid >> 3, sc8 = (tid & 7) * 8;
    __bf16* ptw = &Pt[w][0];

#pragma unroll
    for (int half = 0; half < 2; ++half) {
        const int tile = half ? (31 - tx) : tx;
        const int q0   = tile * 64;

        const int     qrow = q0 + 16 * w + l16;
        const size_t  qoff = (size_t)(b * T_SEQ + qrow) * DM + h * HD;
        bf16x8 qh[2], ql[2];
#pragma unroll
        for (int s = 0; s < 2; ++s) {
            qh[s] = *(const bf16x8*)&qhi[qoff + s * 32 + quad * 8];
            ql[s] = *(const bf16x8*)&qlo[qoff + s * 32 + quad * 8];
        }

        f32x4 o[4];
#pragma unroll
        for (int i = 0; i < 4; ++i) o[i] = (f32x4)0.0f;
        float m_i[4] = {-1e30f, -1e30f, -1e30f, -1e30f};
        float l_i[4] = {0.f, 0.f, 0.f, 0.f};

        for (int j0 = 0; j0 <= q0; j0 += 64) {
            const bool domask = (j0 == q0);
            __syncthreads();
#pragma unroll
            for (int it = 0; it < 2; ++it) {
                int    r = it * 32 + srow;
                size_t gk = (size_t)(b * T_SEQ + j0 + r) * DM + h * HD + sc8;
                *(bf16x8*)&Kh[r * KS + sc8] = *(const bf16x8*)&khi[gk];
                *(bf16x8*)&Kl[r * KS + sc8] = *(const bf16x8*)&klo[gk];
                *(bf16x8*)&Vt[r * KS + sc8] =
                    *(const bf16x8*)&vtg[(size_t)(bh * HD + r) * T_SEQ + j0 + sc8];
            }
            __syncthreads();

            f32x4 sa[4];
#pragma unroll
            for (int i = 0; i < 4; ++i) sa[i] = (f32x4)0.0f;
#pragma unroll
            for (int s = 0; s < 2; ++s) {
#pragma unroll
                for (int ct = 0; ct < 4; ++ct) {
                    bf16x8 kh = *(const bf16x8*)&Kh[(ct * 16 + l16) * KS + s * 32 + quad * 8];
                    bf16x8 kl = *(const bf16x8*)&Kl[(ct * 16 + l16) * KS + s * 32 + quad * 8];
                    sa[ct] = mfma16(qh[s], kh, sa[ct]);
                    sa[ct] = mfma16(ql[s], kh, sa[ct]);
                    sa[ct] = mfma16(qh[s], kl, sa[ct]);
                }
            }

            float p[4][4];
#pragma unroll
            for (int r = 0; r < 4; ++r) {
                const int rq = 16 * w + quad * 4 + r;
                float sc[4];
#pragma unroll
                for (int ct = 0; ct < 4; ++ct) {
                    sc[ct] = sa[ct][r];
                    if (domask && (ct * 16 + l16 > rq)) sc[ct] = -1e30f;
                }
                float rm = fmaxf(fmaxf(sc[0], sc[1]), fmaxf(sc[2], sc[3]));
#pragma unroll
                for (int off = 8; off > 0; off >>= 1) rm = fmaxf(rm, __shfl_xor(rm, off));
                float mn    = fmaxf(m_i[r], rm);
                float alpha = __expf(m_i[r] - mn);
                m_i[r] = mn;
                float rs = 0.f;
#pragma unroll
                for (int ct = 0; ct < 4; ++ct) { p[r][ct] = __expf(sc[ct] - mn); rs += p[r][ct]; }
#pragma unroll
                for (int off = 8; off > 0; off >>= 1) rs += __shfl_xor(rs, off);
                l_i[r] = l_i[r] * alpha + rs;
#pragma unroll
                for (int cb = 0; cb < 4; ++cb) o[cb][r] *= alpha;
            }

#pragma unroll
            for (int ct = 0; ct < 4; ++ct) {
                bf16x2 p01 = { (__bf16)p[0][ct], (__bf16)p[1][ct] };
                bf16x2 p23 = { (__bf16)p[2][ct], (__bf16)p[3][ct] };
                __bf16* base = &ptw[(ct * 16 + l16) * 18 + quad * 4];
                *(bf16x2*)base       = p01;
                *(bf16x2*)(base + 2) = p23;
            }

#pragma unroll
            for (int s = 0; s < 2; ++s) {
                bf16x8 pa;
#pragma unroll
                for (int jj = 0; jj < 8; ++jj)
                    pa[jj] = ptw[(s * 32 + quad * 8 + jj) * 18 + l16];
#pragma unroll
                for (int cb = 0; cb < 4; ++cb) {
                    bf16x8 vf = *(const bf16x8*)&Vt[(cb * 16 + l16) * KS + s * 32 + quad * 8];
                    o[cb] = mfma16(pa, vf, o[cb]);
                }
            }
        }

#pragma unroll
        for (int r = 0; r < 4; ++r) {
            int   qr   = q0 + 16 * w + quad * 4 + r;
            float invl = 1.0f / l_i[r];
#pragma unroll
            for (int cb = 0; cb < 4; ++cb) {
                yb[(size_t)(b * T_SEQ + qr) * DM + h * HD + cb * 16 + l16] =
                    (__bf16)(o[cb][r] * invl);
            }
        }
    }
}

extern "C" void kernel_launch(void* const* d_in, const int* in_sizes, int n_in,
                              void* d_out, int out_size, void* d_ws, size_t ws_size,
                              hipStream_t stream)
{
    (void)in_sizes; (void)n_in; (void)out_size; (void)ws_size;

    const float* x   = (const float*)d_in[0];
    const float* Wq  = (const float*)d_in[2];
    const float* bq  = (const float*)d_in[3];
    const float* Wkv = (const float*)d_in[4];
    const float* bkv = (const float*)d_in[5];
    const float* Wk  = (const float*)d_in[6];
    const float* bk  = (const float*)d_in[7];
    const float* Wv  = (const float*)d_in[8];
    const float* bv  = (const float*)d_in[9];
    const float* Wo  = (const float*)d_in[10];
    const float* bo  = (const float*)d_in[11];
    const float* Wkr = (const float*)d_in[12];

    const int    BT = 2 * T_SEQ;   // 4096
    const size_t MB = 1024 * 1024;
    char* base = (char*)d_ws;

    __bf16* xhi    = (__bf16*)(base +  0 * MB);               // prep -> kv gemm
    __bf16* xlo    = (__bf16*)(base +  8 * MB);               // prep -> kv gemm
    __bf16* qhi    = (__bf16*)(base + 16 * MB);               // q gemm -> attn
    __bf16* qlo    = (__bf16*)(base + 24 * MB);
    __bf16* Wqt_h  = (__bf16*)(base + 32 * MB);               // prep -> q gemm
    __bf16* Wqt_l  = (__bf16*)(base + 34 * MB);
    __bf16* Wkvt_h = (__bf16*)(base + 36 * MB);               // prep -> kv gemm
    __bf16* Wkvt_l = (__bf16*)(base + 37 * MB);
    __bf16* kvhi   = (__bf16*)(base + 38 * MB);               // kv gemm -> v gemm
    __bf16* kvlo   = (__bf16*)(base + 40 * MB);
    __bf16* W2t_h  = (__bf16*)(base + 42 * MB);               // prep -> k gemm
    __bf16* W2t_l  = (__bf16*)(base + 42 * MB + 512 * 1024);
    __bf16* Wvt    = (__bf16*)(base + 43 * MB);               // prep -> v gemm
    __bf16* Wot    = (__bf16*)(base + 43 * MB + 512 * 1024);  // prep -> o gemm (2MB)
    float*  b2     = (float*) (base + 45 * MB + 512 * 1024);  // 4KB
    __bf16* vtg    = (__bf16*)(base +  8 * MB);               // overlays xlo (dead)
    __bf16* ybb    = (__bf16*)(base +  0 * MB);               // overlays xhi (dead)
    __bf16* khi    = (__bf16*)d_out;                          // d_out as scratch (16MB)
    __bf16* klo    = (__bf16*)d_out + (size_t)BT * DM;        // fully rewritten by o gemm

    dim3 blk(256);
    split_x_kernel<<<2048, blk, 0, stream>>>(x, xhi, xlo);
    tsplit<1><<<dim3(16, 16), blk, 0, stream>>>(Wq,  Wqt_h,  Wqt_l,  DM, DM);
    tsplit<1><<<dim3(4, 16),  blk, 0, stream>>>(Wkv, Wkvt_h, Wkvt_l, DM, 256);
    tsplit<0><<<dim3(16, 4),  blk, 0, stream>>>(Wv,  Wvt,    nullptr, 256, DM);
    tsplit<0><<<dim3(16, 16), blk, 0, stream>>>(Wo,  Wot,    nullptr, DM, DM);
    fuse_w2t<<<dim3(257, NH), dim3(64), 0, stream>>>(Wk, Wkr, bk, W2t_h, W2t_l, b2);

    // q = RoPE(x@Wq + bq)*0.125 -> split
    gemm128<1, 1, 2, 1><<<dim3(8, 32), blk, 0, stream>>>(xhi, xlo, Wqt_h, Wqt_l, bq, qhi, qlo, BT, DM, DM);
    // kv = x@Wkv + bkv -> split
    gemm128<1, 1, 2, 0><<<dim3(2, 32), blk, 0, stream>>>(xhi, xlo, Wkvt_h, Wkvt_l, bkv, kvhi, kvlo, BT, 256, DM);
    // k = t*(kv@W2 + b2) -> split (into d_out scratch)
    gemm128<1, 1, 2, 2><<<dim3(8, 32), blk, 0, stream>>>(kvhi, kvlo, W2t_h, W2t_l, b2, khi, klo, BT, DM, 256);
    // v = kv@Wv + bv -> vtg[bh][d][t] (fused transpose epilogue)
    gemm128<0, 0, 0, 3><<<dim3(8, 32), blk, 0, stream>>>(kvhi, nullptr, Wvt, nullptr, bv, vtg, nullptr, BT, DM, 256);
    // flash attention -> y bf16
    attn_v3<<<512, blk, 0, stream>>>(qhi, qlo, khi, klo, vtg, ybb);
    // out = y@Wo + bo -> fp32 d_out (overwrites khi/klo scratch)
    gemm128<0, 0, 1, 0><<<dim3(8, 32), blk, 0, stream>>>(ybb, nullptr, Wot, nullptr, bo, (float*)d_out, nullptr, BT, DM, DM);
}

// Round 8
// 304.130 us; speedup vs baseline: 2.0459x; 1.2913x over previous
//
#include <hip/hip_runtime.h>
#include <hip/hip_bf16.h>
#include <math.h>

typedef __bf16 bf16x8 __attribute__((ext_vector_type(8)));
typedef __bf16 bf16x4 __attribute__((ext_vector_type(4)));
typedef float  f32x4  __attribute__((ext_vector_type(4)));

#define T_SEQ 2048
#define NH    16
#define HD    64
#define DM    1024
// softmax logits pre-scaled by 1/sqrt(64) * log2(e) so we can use exp2
#define QSCALE 0.18033688011112043f

__device__ __forceinline__ f32x4 mfma16(bf16x8 a, bf16x8 b, f32x4 c) {
    return __builtin_amdgcn_mfma_f32_16x16x32_bf16(a, b, c, 0, 0, 0);
}

// ================= prep (one dispatch) =================
__device__ __forceinline__ void tsplit_body(const float* __restrict__ in,
                                            __bf16* __restrict__ oh, __bf16* __restrict__ ol,
                                            int K, int N, int n0, int k0, int SPLIT,
                                            float* tile /* [64][65] LDS */)
{
    const int tid = threadIdx.x;
#pragma unroll
    for (int it = 0; it < 2; ++it) {
        int r = it * 32 + (tid >> 3), c8 = (tid & 7) * 8;
        f32x4 a0 = *(const f32x4*)&in[(size_t)(k0 + r) * N + n0 + c8];
        f32x4 a1 = *(const f32x4*)&in[(size_t)(k0 + r) * N + n0 + c8 + 4];
#pragma unroll
        for (int j = 0; j < 4; ++j) { tile[r * 65 + c8 + j] = a0[j]; tile[r * 65 + c8 + 4 + j] = a1[j]; }
    }
    __syncthreads();
    const int n = tid >> 2, kb = (tid & 3) * 16;
    bf16x8 h0, h1, l0, l1;
#pragma unroll
    for (int j = 0; j < 8; ++j) {
        float v0 = tile[(kb + j) * 65 + n], v1 = tile[(kb + 8 + j) * 65 + n];
        __bf16 hb0 = (__bf16)v0, hb1 = (__bf16)v1;
        h0[j] = hb0; h1[j] = hb1;
        if (SPLIT) { l0[j] = (__bf16)(v0 - (float)hb0); l1[j] = (__bf16)(v1 - (float)hb1); }
    }
    size_t o = (size_t)(n0 + n) * K + k0 + kb;
    *(bf16x8*)&oh[o] = h0; *(bf16x8*)&oh[o + 8] = h1;
    if (SPLIT) { *(bf16x8*)&ol[o] = l0; *(bf16x8*)&ol[o + 8] = l1; }
}

__global__ __launch_bounds__(256)
void prep(const float* __restrict__ x, const float* __restrict__ Wq,
          const float* __restrict__ Wkv, const float* __restrict__ Wv,
          const float* __restrict__ Wo, const float* __restrict__ Wk,
          const float* __restrict__ Wkr, const float* __restrict__ bk,
          __bf16* xh, __bf16* xl, __bf16* Wqt_h, __bf16* Wqt_l,
          __bf16* Wkvt_h, __bf16* Wkvt_l, __bf16* Wvt, __bf16* Wot,
          __bf16* W2th, __bf16* W2tl, float* b2)
{
    __shared__ float tile[64 * 65];
    const int g = blockIdx.x, tid = threadIdx.x;
    if (g < 2048) {                       // split x -> xh/xl
        size_t idx = ((size_t)g * 256 + tid) * 8;
        f32x4 a0 = *(const f32x4*)&x[idx];
        f32x4 a1 = *(const f32x4*)&x[idx + 4];
        bf16x8 h, l;
#pragma unroll
        for (int j = 0; j < 4; ++j) {
            __bf16 h0 = (__bf16)a0[j];
            h[j]     = h0; l[j]     = (__bf16)(a0[j] - (float)h0);
            __bf16 h1 = (__bf16)a1[j];
            h[4 + j] = h1; l[4 + j] = (__bf16)(a1[j] - (float)h1);
        }
        *(bf16x8*)&xh[idx] = h;
        *(bf16x8*)&xl[idx] = l;
    } else if (g < 2304) {                // Wq -> [N,K] split
        int i = g - 2048;
        tsplit_body(Wq, Wqt_h, Wqt_l, 1024, 1024, (i & 15) * 64, (i >> 4) * 64, 1, tile);
    } else if (g < 2368) {                // Wkv -> split
        int i = g - 2304;
        tsplit_body(Wkv, Wkvt_h, Wkvt_l, 1024, 256, (i & 3) * 64, (i >> 2) * 64, 1, tile);
    } else if (g < 2432) {                // Wv -> trunc
        int i = g - 2368;
        tsplit_body(Wv, Wvt, nullptr, 256, 1024, (i & 15) * 64, (i >> 4) * 64, 0, tile);
    } else if (g < 2688) {                // Wo -> trunc
        int i = g - 2432;
        tsplit_body(Wo, Wot, nullptr, 1024, 1024, (i & 15) * 64, (i >> 4) * 64, 0, tile);
    } else {                              // W2 = Wk_h @ Wkr (transposed split) + b2
        int o    = (g - 2688) * 256 + tid;
        int rowk = o >> 10, col = o & 1023;
        int h = col >> 6, d = col & 63;
        float acc = 0.0f;
        if (rowk < 256) {
#pragma unroll 8
            for (int j = 0; j < 64; ++j)
                acc += Wk[(size_t)rowk * DM + h * HD + j] * Wkr[j * HD + d];
            __bf16 hb = (__bf16)acc;
            W2th[(size_t)col * 256 + rowk] = hb;
            W2tl[(size_t)col * 256 + rowk] = (__bf16)(acc - (float)hb);
        } else {
#pragma unroll 8
            for (int j = 0; j < 64; ++j)
                acc += bk[h * HD + j] * Wkr[j * HD + d];
            b2[col] = acc;
        }
    }
}

// ================= 128x128 GEMM body =================
// A bf16 [M,K] (hi + optional lo), B bf16 [N,K] (hi + optional lo)
// OUTM: 0 bf16 | 1 fp32 | 2 dual split bf16
// EPI:  0 bias | 1 RoPE*QSCALE split-out | 2 bias then *t | 3 v->vtg transpose
// NOTE: DUALA/DUALB must be 0 whenever the corresponding lo pointer is not a
// real buffer — r5..r7 passed Blo=nullptr with DUALB=1 in the v-branch, the
// null loads silently killed those waves, vtg stayed poisoned -> y ~ 0.
template <int DUALA, int DUALB, int OUTM, int EPI>
__device__ __forceinline__
void gemm_body(char* smem,
               const __bf16* __restrict__ Ahi, const __bf16* __restrict__ Alo,
               const __bf16* __restrict__ Bhi, const __bf16* __restrict__ Blo,
               const float* __restrict__ bias, void* __restrict__ Cp,
               void* __restrict__ Cp2, int m0, int n0, int N, int K)
{
    __bf16* Ah = (__bf16*)smem;               // [128][32]
    __bf16* Al = (__bf16*)(smem + 8192);
    __bf16* Bh = (__bf16*)(smem + 16384);     // [128][32] = [n][k]
    __bf16* Bl = (__bf16*)(smem + 24576);

    const int tid  = threadIdx.x;
    const int w    = tid >> 6;
    const int lane = tid & 63;
    const int l16  = lane & 15;
    const int quad = lane >> 4;
    const int wy   = w >> 1, wx = w & 1;

    f32x4 acc[4][4];
#pragma unroll
    for (int i = 0; i < 4; ++i)
#pragma unroll
        for (int j = 0; j < 4; ++j) acc[i][j] = (f32x4)0.0f;

    for (int k0 = 0; k0 < K; k0 += 32) {
        __syncthreads();
#pragma unroll
        for (int i = 0; i < 2; ++i) {
            int s = i * 256 + tid, row = s >> 2, c8 = (s & 3) * 8;
            *(bf16x8*)&Ah[row * 32 + c8] = *(const bf16x8*)&Ahi[(size_t)(m0 + row) * K + k0 + c8];
            if (DUALA)
                *(bf16x8*)&Al[row * 32 + c8] = *(const bf16x8*)&Alo[(size_t)(m0 + row) * K + k0 + c8];
            *(bf16x8*)&Bh[row * 32 + c8] = *(const bf16x8*)&Bhi[(size_t)(n0 + row) * K + k0 + c8];
            if (DUALB)
                *(bf16x8*)&Bl[row * 32 + c8] = *(const bf16x8*)&Blo[(size_t)(n0 + row) * K + k0 + c8];
        }
        __syncthreads();

        bf16x8 bfh[4], bfl[4];
#pragma unroll
        for (int ct = 0; ct < 4; ++ct) {
            bfh[ct] = *(const bf16x8*)&Bh[(wx * 64 + ct * 16 + l16) * 32 + quad * 8];
            if (DUALB) bfl[ct] = *(const bf16x8*)&Bl[(wx * 64 + ct * 16 + l16) * 32 + quad * 8];
        }
#pragma unroll
        for (int mf = 0; mf < 4; ++mf) {
            bf16x8 ah = *(const bf16x8*)&Ah[(wy * 64 + mf * 16 + l16) * 32 + quad * 8];
            bf16x8 al;
            if (DUALA) al = *(const bf16x8*)&Al[(wy * 64 + mf * 16 + l16) * 32 + quad * 8];
#pragma unroll
            for (int ct = 0; ct < 4; ++ct) {
                acc[mf][ct] = mfma16(ah, bfh[ct], acc[mf][ct]);
                if (DUALA) acc[mf][ct] = mfma16(al, bfh[ct], acc[mf][ct]);
                if (DUALB) acc[mf][ct] = mfma16(ah, bfl[ct], acc[mf][ct]);
            }
        }
    }

    float bias_v[4];
#pragma unroll
    for (int ct = 0; ct < 4; ++ct)
        bias_v[ct] = bias ? bias[n0 + wx * 64 + ct * 16 + l16] : 0.0f;

    if (EPI == 1) {  // RoPE (q): pair (d, d+32) = (ct, ct+2); *QSCALE; split out
        __bf16* Chi = (__bf16*)Cp;
        __bf16* Clo = (__bf16*)Cp2;
#pragma unroll
        for (int mf = 0; mf < 4; ++mf) {
#pragma unroll
            for (int r = 0; r < 4; ++r) {
                int   m = m0 + wy * 64 + mf * 16 + quad * 4 + r;
                float t = (float)(m & (T_SEQ - 1));
#pragma unroll
                for (int ct = 0; ct < 2; ++ct) {
                    int   d   = ct * 16 + l16;
                    float inv = powf(10000.0f, -(float)d * (1.0f / 32.0f));
                    float sv, cv;
                    sincosf(t * inv, &sv, &cv);
                    float lo = acc[mf][ct][r]     + bias_v[ct];
                    float hi = acc[mf][ct + 2][r] + bias_v[ct + 2];
                    float v0 = (lo * cv - hi * sv) * QSCALE;
                    float v1 = (hi * cv + lo * sv) * QSCALE;
                    size_t i0 = (size_t)m * N + n0 + wx * 64 + d;
                    size_t i1 = i0 + 32;
                    __bf16 h0 = (__bf16)v0, h1 = (__bf16)v1;
                    Chi[i0] = h0; Clo[i0] = (__bf16)(v0 - (float)h0);
                    Chi[i1] = h1; Clo[i1] = (__bf16)(v1 - (float)h1);
                }
            }
        }
    } else if (EPI == 3) {  // v: write vtg[bh][d][t] via per-wave LDS transpose
        __syncthreads();
        __bf16* vt = (__bf16*)(smem + w * 9216);   // [64][72]
#pragma unroll
        for (int mf = 0; mf < 4; ++mf)
#pragma unroll
            for (int ct = 0; ct < 4; ++ct)
#pragma unroll
                for (int r = 0; r < 4; ++r)
                    vt[(ct * 16 + l16) * 72 + mf * 16 + quad * 4 + r] =
                        (__bf16)(acc[mf][ct][r] + bias_v[ct]);
        const int bb   = m0 >> 11;
        const int head = (n0 + wx * 64) >> 6;
        const int bh   = bb * 16 + head;
        __bf16* out    = (__bf16*)Cp;
        size_t  gbase  = ((size_t)(bh * 64 + lane)) * T_SEQ + (m0 & (T_SEQ - 1)) + wy * 64;
#pragma unroll
        for (int j8 = 0; j8 < 8; ++j8)
            *(bf16x8*)&out[gbase + j8 * 8] = *(const bf16x8*)&vt[lane * 72 + j8 * 8];
    } else {
#pragma unroll
        for (int mf = 0; mf < 4; ++mf) {
#pragma unroll
            for (int r = 0; r < 4; ++r) {
                int   m     = m0 + wy * 64 + mf * 16 + quad * 4 + r;
                float scale = (EPI == 2) ? (float)(m & (T_SEQ - 1)) : 1.0f;
#pragma unroll
                for (int ct = 0; ct < 4; ++ct) {
                    float  v   = (acc[mf][ct][r] + bias_v[ct]) * scale;
                    size_t idx = (size_t)m * N + n0 + wx * 64 + ct * 16 + l16;
                    if (OUTM == 1)      ((float*)Cp)[idx]  = v;
                    else if (OUTM == 0) ((__bf16*)Cp)[idx] = (__bf16)v;
                    else {
                        __bf16 hb = (__bf16)v;
                        ((__bf16*)Cp)[idx]  = hb;
                        ((__bf16*)Cp2)[idx] = (__bf16)(v - (float)hb);
                    }
                }
            }
        }
    }
}

// merged q + kv gemm: grid (10, 32)
__global__ __launch_bounds__(256)
void gemm_qkv(const __bf16* xh, const __bf16* xl,
              const __bf16* Wqt_h, const __bf16* Wqt_l, const float* bq,
              __bf16* qhi, __bf16* qlo,
              const __bf16* Wkvt_h, const __bf16* Wkvt_l, const float* bkv,
              __bf16* kvhi, __bf16* kvlo)
{
    __shared__ __attribute__((aligned(16))) char smem[36864];
    const int m0 = blockIdx.y * 128;
    if (blockIdx.x < 8)
        gemm_body<1, 1, 2, 1>(smem, xh, xl, Wqt_h, Wqt_l, bq, qhi, qlo,
                              m0, blockIdx.x * 128, 1024, 1024);
    else
        gemm_body<1, 1, 2, 0>(smem, xh, xl, Wkvt_h, Wkvt_l, bkv, kvhi, kvlo,
                              m0, (blockIdx.x - 8) * 128, 256, 1024);
}

// merged k + v gemm: grid (16, 32)
__global__ __launch_bounds__(256)
void gemm_kv2(const __bf16* kvhi, const __bf16* kvlo,
              const __bf16* W2th, const __bf16* W2tl, const float* b2,
              __bf16* khi, __bf16* klo,
              const __bf16* Wvt, const float* bv, __bf16* vtg)
{
    __shared__ __attribute__((aligned(16))) char smem[36864];
    const int m0 = blockIdx.y * 128;
    if (blockIdx.x < 8)
        gemm_body<1, 1, 2, 2>(smem, kvhi, kvlo, W2th, W2tl, b2, khi, klo,
                              m0, blockIdx.x * 128, 1024, 256);
    else
        // DUALB=0: Wvt is trunc-only; never pass nullptr with DUAL*=1 (r5-r7 bug)
        gemm_body<1, 0, 0, 3>(smem, kvhi, kvlo, Wvt, Wvt, bv, vtg, nullptr,
                              m0, (blockIdx.x - 8) * 128, 1024, 256);
}

// o gemm: grid (8, 32)
__global__ __launch_bounds__(256)
void gemm_o(const __bf16* ybb, const __bf16* Wot, const float* bo, float* out)
{
    __shared__ __attribute__((aligned(16))) char smem[36864];
    gemm_body<0, 0, 1, 0>(smem, ybb, ybb, Wot, Wot, bo, out, nullptr,
                          blockIdx.y * 128, blockIdx.x * 128, 1024, 1024);
}

// ================= flash attention v4c =================
// Transposed dataflow: S^T = K Q^T, O^T = V^T P^T.
// Row max/sum need cross-quad shfl_xor(16,32) (r5 NaN fix).
// PSP keeps rows 16B-aligned: stride 72 elems = 144 B = 9*16 (r6 bug: PSP=76).
#define KSP 72
#define PSP 72
__global__ __launch_bounds__(256, 3)
void attn_v4(const __bf16* __restrict__ qhi, const __bf16* __restrict__ qlo,
             const __bf16* __restrict__ khi, const __bf16* __restrict__ klo,
             const __bf16* __restrict__ vtg, __bf16* __restrict__ yb)
{
    __shared__ __attribute__((aligned(16))) __bf16 Kh[64 * KSP];
    __shared__ __attribute__((aligned(16))) __bf16 Kl[64 * KSP];
    __shared__ __attribute__((aligned(16))) __bf16 Vt[64 * KSP];       // [d][key]
    __shared__ __attribute__((aligned(16))) __bf16 Pw[4][2][16 * PSP]; // [wave][frag][qrow][key]

    const int tid  = threadIdx.x;
    const int w    = tid >> 6;
    const int lane = tid & 63;
    const int l16  = lane & 15;
    const int quad = lane >> 4;

    // bh = g&31 (XCD-stable); tiles paired (15-2a, 2(a-8)) so co-resident pairs sum to 34 steps
    const int g  = blockIdx.x;
    const int bh = g & 31, a = g >> 5;
    const int tile = (a < 8) ? (15 - 2 * a) : (2 * (a - 8));
    const int b = bh >> 4, h = bh & 15;
    const int q0 = tile * 128;

    // Q B-frags (pre-scaled by QSCALE), 2 frags x 2 k-halves
    bf16x8 qh[2][2], ql[2][2];
#pragma unroll
    for (int f = 0; f < 2; ++f) {
        const int    qrow = q0 + 64 * f + 16 * w + l16;
        const size_t qoff = (size_t)(b * T_SEQ + qrow) * DM + h * HD;
#pragma unroll
        for (int s = 0; s < 2; ++s) {
            qh[f][s] = *(const bf16x8*)&qhi[qoff + s * 32 + quad * 8];
            ql[f][s] = *(const bf16x8*)&qlo[qoff + s * 32 + quad * 8];
        }
    }

    f32x4 o[2][4];
#pragma unroll
    for (int f = 0; f < 2; ++f)
#pragma unroll
        for (int i = 0; i < 4; ++i) o[f][i] = (f32x4)0.0f;
    float m_i[2] = {-1e30f, -1e30f}, l_i[2] = {0.f, 0.f};

    const int srow = tid >> 3, sc8 = (tid & 7) * 8;

    for (int j0 = 0; j0 <= q0 + 64; j0 += 64) {
        const bool act0 = (j0 <= q0);   // frag0 fully masked on final step
        __syncthreads();
#pragma unroll
        for (int it = 0; it < 2; ++it) {
            int    r  = it * 32 + srow;
            size_t gk = (size_t)(b * T_SEQ + j0 + r) * DM + h * HD + sc8;
            *(bf16x8*)&Kh[r * KSP + sc8] = *(const bf16x8*)&khi[gk];
            *(bf16x8*)&Kl[r * KSP + sc8] = *(const bf16x8*)&klo[gk];
            *(bf16x8*)&Vt[r * KSP + sc8] =
                *(const bf16x8*)&vtg[(size_t)(bh * HD + r) * T_SEQ + j0 + sc8];
        }
        __syncthreads();

        // S^T = K Q^T: rows=keys (kc,quad,reg), cols=qrows (l16)
        f32x4 sa[2][4];
#pragma unroll
        for (int f = 0; f < 2; ++f)
#pragma unroll
            for (int i = 0; i < 4; ++i) sa[f][i] = (f32x4)0.0f;
#pragma unroll
        for (int s = 0; s < 2; ++s) {
#pragma unroll
            for (int kc = 0; kc < 4; ++kc) {
                bf16x8 kh = *(const bf16x8*)&Kh[(kc * 16 + l16) * KSP + s * 32 + quad * 8];
                bf16x8 kv = *(const bf16x8*)&Kl[(kc * 16 + l16) * KSP + s * 32 + quad * 8];
                sa[1][kc] = mfma16(kh, qh[1][s], sa[1][kc]);
                sa[1][kc] = mfma16(kv, qh[1][s], sa[1][kc]);
                sa[1][kc] = mfma16(kh, ql[1][s], sa[1][kc]);
                if (act0) {
                    sa[0][kc] = mfma16(kh, qh[0][s], sa[0][kc]);
                    sa[0][kc] = mfma16(kv, qh[0][s], sa[0][kc]);
                    sa[0][kc] = mfma16(kh, ql[0][s], sa[0][kc]);
                }
            }
        }

        // online softmax per frag; row state shared across the 4 quads that
        // hold this q-row's keys -> cross-quad shfl_xor(16,32) reductions
#pragma unroll
        for (int f = 0; f < 2; ++f) {
            if (f == 0 && !act0) continue;
            const int  qrow = q0 + 64 * f + 16 * w + l16;
            const bool need = (j0 + 63 > q0 + 64 * f + 16 * w);
            if (need) {
#pragma unroll
                for (int kc = 0; kc < 4; ++kc)
#pragma unroll
                    for (int r = 0; r < 4; ++r)
                        if (j0 + kc * 16 + quad * 4 + r > qrow) sa[f][kc][r] = -1e30f;
            }
            float mx = -1e30f;
#pragma unroll
            for (int kc = 0; kc < 4; ++kc)
#pragma unroll
                for (int r = 0; r < 4; ++r) mx = fmaxf(mx, sa[f][kc][r]);
            mx = fmaxf(mx, __shfl_xor(mx, 16));
            mx = fmaxf(mx, __shfl_xor(mx, 32));
            float mn    = fmaxf(fmaxf(m_i[f], mx), -1e20f);
            float alpha = exp2f(m_i[f] - mn);
            m_i[f] = mn;
            float rs = 0.f;
            __bf16* pw = &Pw[w][f][0];
#pragma unroll
            for (int kc = 0; kc < 4; ++kc) {
                float p0 = exp2f(sa[f][kc][0] - mn);
                float p1 = exp2f(sa[f][kc][1] - mn);
                float p2 = exp2f(sa[f][kc][2] - mn);
                float p3 = exp2f(sa[f][kc][3] - mn);
                rs += (p0 + p1) + (p2 + p3);
                bf16x4 pk = { (__bf16)p0, (__bf16)p1, (__bf16)p2, (__bf16)p3 };
                *(bf16x4*)&pw[l16 * PSP + kc * 16 + quad * 4] = pk;
            }
            rs += __shfl_xor(rs, 16);
            rs += __shfl_xor(rs, 32);
            l_i[f] = l_i[f] * alpha + rs;
#pragma unroll
            for (int dc = 0; dc < 4; ++dc) o[f][dc] *= alpha;
        }

        // O^T += V^T P^T: rows=d (dc,quad,reg), cols=qrows (l16)
#pragma unroll
        for (int s = 0; s < 2; ++s) {
            bf16x8 pb1 = *(const bf16x8*)&Pw[w][1][l16 * PSP + s * 32 + quad * 8];
            bf16x8 pb0;
            if (act0) pb0 = *(const bf16x8*)&Pw[w][0][l16 * PSP + s * 32 + quad * 8];
#pragma unroll
            for (int dc = 0; dc < 4; ++dc) {
                bf16x8 va = *(const bf16x8*)&Vt[(dc * 16 + l16) * KSP + s * 32 + quad * 8];
                o[1][dc] = mfma16(va, pb1, o[1][dc]);
                if (act0) o[0][dc] = mfma16(va, pb0, o[0][dc]);
            }
        }
    }

    // epilogue: normalize, transpose via per-wave P buffer, coalesced store
#pragma unroll
    for (int f = 0; f < 2; ++f) {
        float   invl = 1.0f / l_i[f];
        __bf16* pw   = &Pw[w][f][0];
#pragma unroll
        for (int dc = 0; dc < 4; ++dc) {
            bf16x4 ov = { (__bf16)(o[f][dc][0] * invl), (__bf16)(o[f][dc][1] * invl),
                          (__bf16)(o[f][dc][2] * invl), (__bf16)(o[f][dc][3] * invl) };
            *(bf16x4*)&pw[l16 * PSP + dc * 16 + quad * 4] = ov;
        }
        const int qrl  = lane >> 2;          // 0..15
        const int dch  = (lane & 3) * 16;    // 0,16,32,48
        const int qrow = q0 + 64 * f + 16 * w + qrl;
        const __bf16* src = &pw[qrl * PSP + dch];
        __bf16*       dst = &yb[(size_t)(b * T_SEQ + qrow) * DM + h * HD + dch];
        *(bf16x8*)dst       = *(const bf16x8*)src;
        *(bf16x8*)(dst + 8) = *(const bf16x8*)(src + 8);
    }
}

extern "C" void kernel_launch(void* const* d_in, const int* in_sizes, int n_in,
                              void* d_out, int out_size, void* d_ws, size_t ws_size,
                              hipStream_t stream)
{
    (void)in_sizes; (void)n_in; (void)out_size; (void)ws_size;

    const float* x   = (const float*)d_in[0];
    const float* Wq  = (const float*)d_in[2];
    const float* bq  = (const float*)d_in[3];
    const float* Wkv = (const float*)d_in[4];
    const float* bkv = (const float*)d_in[5];
    const float* Wk  = (const float*)d_in[6];
    const float* bk  = (const float*)d_in[7];
    const float* Wv  = (const float*)d_in[8];
    const float* bv  = (const float*)d_in[9];
    const float* Wo  = (const float*)d_in[10];
    const float* bo  = (const float*)d_in[11];
    const float* Wkr = (const float*)d_in[12];

    const int    BT = 2 * T_SEQ;   // 4096
    const size_t MB = 1024 * 1024;
    char* base = (char*)d_ws;

    __bf16* xhi    = (__bf16*)(base +  0 * MB);
    __bf16* xlo    = (__bf16*)(base +  8 * MB);
    __bf16* qhi    = (__bf16*)(base + 16 * MB);
    __bf16* qlo    = (__bf16*)(base + 24 * MB);
    __bf16* Wqt_h  = (__bf16*)(base + 32 * MB);
    __bf16* Wqt_l  = (__bf16*)(base + 34 * MB);
    __bf16* Wkvt_h = (__bf16*)(base + 36 * MB);
    __bf16* Wkvt_l = (__bf16*)(base + 37 * MB);
    __bf16* kvhi   = (__bf16*)(base + 38 * MB);
    __bf16* kvlo   = (__bf16*)(base + 40 * MB);
    __bf16* W2t_h  = (__bf16*)(base + 42 * MB);
    __bf16* W2t_l  = (__bf16*)(base + 42 * MB + 512 * 1024);
    __bf16* Wvt    = (__bf16*)(base + 43 * MB);
    __bf16* Wot    = (__bf16*)(base + 43 * MB + 512 * 1024);
    float*  b2     = (float*) (base + 45 * MB + 512 * 1024);
    __bf16* vtg    = (__bf16*)(base +  8 * MB);               // overlays xlo (dead)
    __bf16* ybb    = (__bf16*)(base +  0 * MB);               // overlays xhi (dead)
    __bf16* khi    = (__bf16*)d_out;                          // d_out as scratch
    __bf16* klo    = (__bf16*)d_out + (size_t)BT * DM;        // overwritten by o gemm

    dim3 blk(256);
    prep<<<3716, blk, 0, stream>>>(x, Wq, Wkv, Wv, Wo, Wk, Wkr, bk,
                                   xhi, xlo, Wqt_h, Wqt_l, Wkvt_h, Wkvt_l,
                                   Wvt, Wot, W2t_h, W2t_l, b2);
    gemm_qkv<<<dim3(10, 32), blk, 0, stream>>>(xhi, xlo, Wqt_h, Wqt_l, bq, qhi, qlo,
                                               Wkvt_h, Wkvt_l, bkv, kvhi, kvlo);
    gemm_kv2<<<dim3(16, 32), blk, 0, stream>>>(kvhi, kvlo, W2t_h, W2t_l, b2,
                                               khi, klo, Wvt, bv, vtg);
    attn_v4<<<512, blk, 0, stream>>>(qhi, qlo, khi, klo, vtg, ybb);
    gemm_o<<<dim3(8, 32), blk, 0, stream>>>(ybb, Wot, bo, (float*)d_out);
}